// Round 6
// baseline (85.399 us; speedup 1.0000x reference)
//
#include <hip/hip_runtime.h>
#include <math.h>

// SACConv: B=8, C1=C2=16, K=3, S=1, H=W=64, HDIM=16, N=C1*K*K=144, L=4096
//
// out[b,l,c] = Qb[l,c] + sum_j h[l,j]*Qw[l,c*16+j]
//   Q[32768 x 272] = P[32768 x 144] @ Wcat[144 x 272]   (bf16 MFMA, K padded 160)
//   cols 0..255: (c,j) -> c*16+j from fc2_w ; cols 256..271: bias col c
//
// R6: fully wave-synchronous. 2048 blocks x 64 threads; block = 1 wave = one
// 16-loc m-tile. Lane (m=lane&15, q=lane>>4) loads its OWN A-fragment elements
// o = 32s+8q+j straight from x (no LDS staging, no barriers). Stats reduced
// across the 4 lanes per loc via __shfl_xor(16/32). Single __syncthreads()
// around the Q LDS dump (1-wave block -> barrier is just a drain). 8
// independent blocks/CU hide load latency across blocks.

typedef __attribute__((ext_vector_type(8))) short short8;
typedef __attribute__((ext_vector_type(4))) float float4v;

#define NPq 144

__device__ __forceinline__ unsigned short f2bf(float f) {
    unsigned int u = __builtin_bit_cast(unsigned int, f);
    u += 0x7fffu + ((u >> 16) & 1u);
    return (unsigned short)(u >> 16);
}
__device__ __forceinline__ float bf2f(unsigned short h) {
    unsigned int u = ((unsigned int)h) << 16;
    return __builtin_bit_cast(float, u);
}

// ---------- prep: B fragments (unchanged, validated R3-R5) ----------
// Bfrag[(t*5+s)*64 + lane] = 8 bf16 of B[k = s*32+(lane>>4)*8+j][n = lane&15]
// t<16: B[k][n] = fc2_w[(t*144+k)*16+n]; t==16: fc2_b[n*144+k]; k>=144 -> 0
__global__ void prep_bfrag(const float* __restrict__ fc2_w,
                           const float* __restrict__ fc2_b,
                           unsigned short* __restrict__ Bfrag) {
    const int blk  = blockIdx.x;           // 85 = 17*5
    const int t    = blk / 5, s = blk % 5;
    const int lane = threadIdx.x;          // 64
    const int n    = lane & 15, q = lane >> 4;
    short8 v;
#pragma unroll
    for (int j = 0; j < 8; ++j) {
        const int k = s * 32 + q * 8 + j;
        float w = 0.f;
        if (k < NPq) w = (t < 16) ? fc2_w[(t * NPq + k) * 16 + n]
                                  : fc2_b[n * NPq + k];
        v[j] = (short)f2bf(w);
    }
    *(short8*)(Bfrag + (size_t)(blk * 64 + lane) * 8) = v;
}

// ---------- main ----------
__global__ __launch_bounds__(64, 2) void sacconv_kernel(
    const float* __restrict__ x,
    const float* __restrict__ fc1_w,
    const float* __restrict__ fc1_b,
    const unsigned short* __restrict__ Bfrag,
    float* __restrict__ out)
{
    __shared__ unsigned short Qs[16 * 288];   // 9216 B; stride 288 keeps b128 alignment

    const int lane = threadIdx.x;
    const int blk  = blockIdx.x;      // 2048
    const int b    = blk >> 8;        // image
    const int y    = (blk >> 2) & 63; // row
    const int x0   = (blk & 3) << 4;  // quarter-row base col

    const int m  = lane & 15;         // loc within tile (= A-frag m)
    const int q  = lane >> 4;         // A-frag k-quad
    const int xm = x0 + m;

    // ---------- load own A-frag elements + pass-A stats ----------
    float v[5][8];
    short8 af[5];
    float sum = 0.f, mx = -1e30f;
#pragma unroll
    for (int s = 0; s < 5; ++s) {
#pragma unroll
        for (int j = 0; j < 8; ++j) {
            const int o = s * 32 + q * 8 + j;    // runtime in q only
            float val = 0.f;
            if (o < NPq) {                        // s<4: always true (folds away)
                const int c1 = o / 9;
                const int rm = o - c1 * 9;
                const int ii = rm / 3;
                const int jj = rm - ii * 3;
                const int yy = y + ii - 1;
                const int xp = xm + jj - 1;
                if (yy >= 0 && yy < 64 && xp >= 0 && xp < 64)
                    val = x[((b * 16 + c1) * 64 + yy) * 64 + xp];
                sum += val;
                mx = fmaxf(mx, val);
            }
            v[s][j] = val;
            af[s][j] = (short)f2bf(val);
        }
    }
    // reduce across the 4 lanes (m, m+16, m+32, m+48) sharing this loc
    sum += __shfl_xor(sum, 16, 64);
    sum += __shfl_xor(sum, 32, 64);
    mx = fmaxf(mx, __shfl_xor(mx, 16, 64));
    mx = fmaxf(mx, __shfl_xor(mx, 32, 64));
    const float mu = sum * (1.f / 144.f);

    // ---------- pass B: central moments + exp sums ----------
    float m2 = 0.f, m3 = 0.f, m4 = 0.f, se = 0.f, sev = 0.f;
#pragma unroll
    for (int s = 0; s < 5; ++s) {
#pragma unroll
        for (int j = 0; j < 8; ++j) {
            const int o = s * 32 + q * 8 + j;
            if (o < NPq) {
                const float d  = v[s][j] - mu;
                const float d2 = d * d;
                m2 += d2; m3 += d2 * d; m4 += d2 * d2;
                const float e = __expf(v[s][j] - mx);
                se += e; sev += e * v[s][j];
            }
        }
    }
    m2 += __shfl_xor(m2, 16, 64);  m2 += __shfl_xor(m2, 32, 64);
    m3 += __shfl_xor(m3, 16, 64);  m3 += __shfl_xor(m3, 32, 64);
    m4 += __shfl_xor(m4, 16, 64);  m4 += __shfl_xor(m4, 32, 64);
    se += __shfl_xor(se, 16, 64);  se += __shfl_xor(se, 32, 64);
    sev += __shfl_xor(sev, 16, 64); sev += __shfl_xor(sev, 32, 64);

    // final per-loc stats (each of the 4 lanes computes identically)
    const float var   = m2 * (1.f / 143.f);           // ddof=1
    const float sigma = sqrtf(var) + 1e-6f;
    const float is    = 1.f / sigma;
    const float is2   = is * is;
    const float skew  = (m3 * (1.f / 144.f)) * is2 * is;
    const float kurt  = (m4 * (1.f / 144.f)) * is2 * is2 - 3.f;
    const float ent   = __logf(se) + mx - sev / se;   // -sum p ln p (validated R5)

    // ---------- MFMA: 17 n-tiles x 5 K-steps, B prefetch distance 1 ----------
    float4v acc[17];
#pragma unroll
    for (int tt = 0; tt < 17; ++tt) acc[tt] = (float4v){0.f, 0.f, 0.f, 0.f};

    const short8* Bf = (const short8*)Bfrag;
    short8 bcur[5], bnxt[5];
#pragma unroll
    for (int s = 0; s < 5; ++s) bcur[s] = Bf[s * 64 + lane];

#pragma unroll
    for (int tt = 0; tt < 17; ++tt) {
        if (tt < 16) {
#pragma unroll
            for (int s = 0; s < 5; ++s) bnxt[s] = Bf[((tt + 1) * 5 + s) * 64 + lane];
        }
#pragma unroll
        for (int s = 0; s < 5; ++s)
            acc[tt] = __builtin_amdgcn_mfma_f32_16x16x32_bf16(af[s], bcur[s], acc[tt], 0, 0, 0);
        if (tt < 16) {
#pragma unroll
            for (int s = 0; s < 5; ++s) bcur[s] = bnxt[s];
        }
    }

    // ---------- dump Q to LDS (bf16); C layout: col=lane&15, row=(lane>>4)*4+r ----------
    {
        const int nn = lane & 15, qq = lane >> 4;
#pragma unroll
        for (int tt = 0; tt < 17; ++tt) {
#pragma unroll
            for (int r = 0; r < 4; ++r)
                Qs[(qq * 4 + r) * 288 + tt * 16 + nn] = f2bf(acc[tt][r]);
        }
    }
    __syncthreads();   // 1-wave block: just drains lgkm before cross-lane reads

    // ---------- h (deferred to cut MFMA-phase VGPR pressure), fold, store ----------
    {
        float h[16];
#pragma unroll
        for (int j = 0; j < 16; ++j) {
            const float* wr = fc1_w + j * 5;
            const float hv = mu * wr[0] + sigma * wr[1] + skew * wr[2]
                           + kurt * wr[3] + ent * wr[4] + fc1_b[j];
            h[j] = fmaxf(hv, 0.f);
        }
        // lane handles loc = m (its own stats/h), c-group = q*4 .. q*4+3
#pragma unroll
        for (int cc = 0; cc < 4; ++cc) {
            const int c = q * 4 + cc;
            const unsigned short* qr = &Qs[m * 288 + c * 16];
            short8 q0 = *(const short8*)qr;
            short8 q1 = *(const short8*)(qr + 8);
            float res = bf2f(Qs[m * 288 + 256 + c]);
#pragma unroll
            for (int j = 0; j < 8; ++j) res += h[j]     * bf2f((unsigned short)q0[j]);
#pragma unroll
            for (int j = 0; j < 8; ++j) res += h[8 + j] * bf2f((unsigned short)q1[j]);
            out[(b * 16 + c) * 4096 + y * 64 + x0 + m] = res;
        }
    }
}

extern "C" void kernel_launch(void* const* d_in, const int* in_sizes, int n_in,
                              void* d_out, int out_size, void* d_ws, size_t ws_size,
                              hipStream_t stream) {
    const float* x     = (const float*)d_in[0];
    const float* fc1_w = (const float*)d_in[1];
    const float* fc1_b = (const float*)d_in[2];
    const float* fc2_w = (const float*)d_in[3];
    const float* fc2_b = (const float*)d_in[4];
    float* out = (float*)d_out;
    unsigned short* Bfrag = (unsigned short*)d_ws;   // 85*64*8*2 = 87040 B

    prep_bfrag<<<85, 64, 0, stream>>>(fc2_w, fc2_b, Bfrag);
    sacconv_kernel<<<2048, 64, 0, stream>>>(x, fc1_w, fc1_b, Bfrag, out);
}

// Round 7
// 75.402 us; speedup vs baseline: 1.1326x; 1.1326x over previous
//
#include <hip/hip_runtime.h>
#include <math.h>

// SACConv: B=8, C1=C2=16, K=3, S=1, H=W=64, HDIM=16, N=C1*K*K=144, L=4096
//
// out[b,l,c] = Qb[l,c] + sum_j h[l,j]*Qw[l,c*16+j]
//   Q[32768 x 272] = P[32768 x 144] @ Wcat[144 x 272]   (bf16 MFMA, K padded 160)
//   cols 0..255: (c,j) -> c*16+j from fc2_w ; cols 256..271: bias col c
//
// R7 = R5 MFMA structure + R6 barrier-free stats:
//  - lane (m,q) of wave w owns loc w*16+m, loads A-frag elems o=32s+8q+j
//    direct from x; stats via __shfl_xor(16/32); NO stats barriers.
//  - wave stages its own m-tile A-frags (5 ds_write_b128) + h to LDS; barrier 1.
//  - MFMA: wave (mp=w>>1, nh=w&1) does m-pair x 9 n-tiles (B dedup x2, R5-validated).
//  - Q dump to separate LDS region (no alias -> no pre-dump barrier); barrier 2; fold.

typedef __attribute__((ext_vector_type(8))) short short8;
typedef __attribute__((ext_vector_type(4))) float float4v;

#define NPq 144

__device__ __forceinline__ unsigned short f2bf(float f) {
    unsigned int u = __builtin_bit_cast(unsigned int, f);
    u += 0x7fffu + ((u >> 16) & 1u);
    return (unsigned short)(u >> 16);
}
__device__ __forceinline__ float bf2f(unsigned short h) {
    unsigned int u = ((unsigned int)h) << 16;
    return __builtin_bit_cast(float, u);
}

// ---------- prep: B fragments (unchanged, validated R3-R6) ----------
// Bfrag[(t*5+s)*64 + lane] = 8 bf16 of B[k = s*32+(lane>>4)*8+j][n = lane&15]
// t<16: B[k][n] = fc2_w[(t*144+k)*16+n]; t==16: fc2_b[n*144+k]; k>=144 -> 0
__global__ void prep_bfrag(const float* __restrict__ fc2_w,
                           const float* __restrict__ fc2_b,
                           unsigned short* __restrict__ Bfrag) {
    const int blk  = blockIdx.x;           // 85 = 17*5
    const int t    = blk / 5, s = blk % 5;
    const int lane = threadIdx.x;          // 64
    const int n    = lane & 15, q = lane >> 4;
    short8 v;
#pragma unroll
    for (int j = 0; j < 8; ++j) {
        const int k = s * 32 + q * 8 + j;
        float w = 0.f;
        if (k < NPq) w = (t < 16) ? fc2_w[(t * NPq + k) * 16 + n]
                                  : fc2_b[n * NPq + k];
        v[j] = (short)f2bf(w);
    }
    *(short8*)(Bfrag + (size_t)(blk * 64 + lane) * 8) = v;
}

// ---------- main ----------
__global__ __launch_bounds__(256, 2) void sacconv_kernel(
    const float* __restrict__ x,
    const float* __restrict__ fc1_w,
    const float* __restrict__ fc1_b,
    const unsigned short* __restrict__ Bfrag,
    float* __restrict__ out)
{
    __shared__ unsigned short SA[4 * 5 * 64 * 8];   // A-frags, 20480 B
    __shared__ unsigned short Qs[64 * 280];         // Q dump,  35840 B
    __shared__ float Hl[64][20];                    // h,        5120 B  (60 KB total)

    const int t   = threadIdx.x;
    const int blk = blockIdx.x;     // 512
    const int b   = blk >> 6;
    const int y   = blk & 63;

    const int lane = t & 63;
    const int w    = __builtin_amdgcn_readfirstlane(t >> 6);   // wave id, uniform
    const int m    = lane & 15;     // loc within this wave's m-tile
    const int q    = lane >> 4;     // A-frag k-quad
    const int loc  = w * 16 + m;    // this lane's column / location

    // ---------- load own A-frag elements + pass-A stats (no LDS, no barriers) ----------
    float v[5][8];
    short8 af[5];
    float sum = 0.f, mx = -1e30f;
#pragma unroll
    for (int s = 0; s < 5; ++s) {
#pragma unroll
        for (int j = 0; j < 8; ++j) {
            const int o = s * 32 + q * 8 + j;    // runtime in q only
            float val = 0.f;
            if (o < NPq) {                        // s<4 folds away; s=4 masks K-pad
                const int c1 = o / 9;
                const int rm = o - c1 * 9;
                const int ii = rm / 3;
                const int jj = rm - ii * 3;
                const int yy = y + ii - 1;
                const int xp = loc + jj - 1;
                if (yy >= 0 && yy < 64 && xp >= 0 && xp < 64)
                    val = x[((b * 16 + c1) * 64 + yy) * 64 + xp];
                sum += val;
                mx = fmaxf(mx, val);
            }
            v[s][j] = val;
            af[s][j] = (short)f2bf(val);
        }
    }
    // reduce across the 4 lanes (m, m+16, m+32, m+48) sharing this loc
    sum += __shfl_xor(sum, 16, 64);
    sum += __shfl_xor(sum, 32, 64);
    mx = fmaxf(mx, __shfl_xor(mx, 16, 64));
    mx = fmaxf(mx, __shfl_xor(mx, 32, 64));
    const float mu = sum * (1.f / 144.f);

    // ---------- pass B: central moments + exp sums (registers only) ----------
    float m2 = 0.f, m3 = 0.f, m4 = 0.f, se = 0.f, sev = 0.f;
#pragma unroll
    for (int s = 0; s < 5; ++s) {
#pragma unroll
        for (int j = 0; j < 8; ++j) {
            const int o = s * 32 + q * 8 + j;
            if (o < NPq) {
                const float d  = v[s][j] - mu;
                const float d2 = d * d;
                m2 += d2; m3 += d2 * d; m4 += d2 * d2;
                const float e = __expf(v[s][j] - mx);
                se += e; sev += e * v[s][j];
            }
        }
    }
    m2 += __shfl_xor(m2, 16, 64);  m2 += __shfl_xor(m2, 32, 64);
    m3 += __shfl_xor(m3, 16, 64);  m3 += __shfl_xor(m3, 32, 64);
    m4 += __shfl_xor(m4, 16, 64);  m4 += __shfl_xor(m4, 32, 64);
    se += __shfl_xor(se, 16, 64);  se += __shfl_xor(se, 32, 64);
    sev += __shfl_xor(sev, 16, 64); sev += __shfl_xor(sev, 32, 64);

    // per-loc stats (all 4 lanes of a loc compute identically)
    const float var   = m2 * (1.f / 143.f);           // ddof=1
    const float sigma = sqrtf(var) + 1e-6f;
    const float is    = 1.f / sigma;
    const float is2   = is * is;
    const float skew  = (m3 * (1.f / 144.f)) * is2 * is;
    const float kurt  = (m4 * (1.f / 144.f)) * is2 * is2 - 3.f;
    const float ent   = __logf(se) + mx - sev / se;   // validated R5/R6

    // ---------- h for this loc: lane (m,q) computes j = q*4..q*4+3 ----------
    {
        float h4[4];
#pragma unroll
        for (int j0 = 0; j0 < 4; ++j0) {
            const int j = q * 4 + j0;
            const float* wr = fc1_w + j * 5;
            const float hv = mu * wr[0] + sigma * wr[1] + skew * wr[2]
                           + kurt * wr[3] + ent * wr[4] + fc1_b[j];
            h4[j0] = fmaxf(hv, 0.f);
        }
        *(float4*)&Hl[loc][q * 4] = make_float4(h4[0], h4[1], h4[2], h4[3]);
    }

    // ---------- stage own m-tile A-frags (K-pad zeros included via mask) ----------
#pragma unroll
    for (int s = 0; s < 5; ++s)
        *(short8*)&SA[((w * 5 + s) * 64 + lane) * 8] = af[s];

    __syncthreads();   // barrier 1: A-frags + Hl visible to all waves

    // ---------- MFMA: wave (mp, nh) -> m-tiles {2mp,2mp+1} x n-tiles {8nh..8nh+8} ----------
    const int mp = w >> 1;
    const int nh = w & 1;
    const int nb = nh * 8;            // tile 8 computed by both halves (bit-identical)

    short8 af2[2][5];
#pragma unroll
    for (int mm = 0; mm < 2; ++mm)
#pragma unroll
        for (int s = 0; s < 5; ++s)
            af2[mm][s] = *(const short8*)&SA[(((2 * mp + mm) * 5 + s) * 64 + lane) * 8];

    float4v acc[18];
#pragma unroll
    for (int i = 0; i < 18; ++i) acc[i] = (float4v){0.f, 0.f, 0.f, 0.f};

    const short8* Bf = (const short8*)Bfrag;
    short8 bcur[5], bnxt[5];
#pragma unroll
    for (int s = 0; s < 5; ++s) bcur[s] = Bf[(nb * 5 + s) * 64 + lane];

#pragma unroll
    for (int u = 0; u < 9; ++u) {
        if (u < 8) {
#pragma unroll
            for (int s = 0; s < 5; ++s) bnxt[s] = Bf[((nb + u + 1) * 5 + s) * 64 + lane];
        }
#pragma unroll
        for (int mm = 0; mm < 2; ++mm)
#pragma unroll
            for (int s = 0; s < 5; ++s)
                acc[u * 2 + mm] = __builtin_amdgcn_mfma_f32_16x16x32_bf16(
                    af2[mm][s], bcur[s], acc[u * 2 + mm], 0, 0, 0);
        if (u < 8) {
#pragma unroll
            for (int s = 0; s < 5; ++s) bcur[s] = bnxt[s];
        }
    }

    // ---------- dump Q to its own LDS region (no pre-barrier needed) ----------
    {
        const int nn = lane & 15, qq = lane >> 4;
#pragma unroll
        for (int u = 0; u < 9; ++u) {
            const int col = (nb + u) * 16 + nn;   // tile 16 -> cols 256..271 (bias)
#pragma unroll
            for (int mm = 0; mm < 2; ++mm) {
                const int rowb = (2 * mp + mm) * 16 + qq * 4;
#pragma unroll
                for (int r = 0; r < 4; ++r)
                    Qs[(rowb + r) * 280 + col] = f2bf(acc[u * 2 + mm][r]);
            }
        }
    }
    __syncthreads();   // barrier 2: Q complete

    // ---------- fold h, write out (each lane: its own loc = lane, c-group w*4..) ----------
    {
        float hv[16];
#pragma unroll
        for (int j = 0; j < 16; ++j) hv[j] = Hl[lane][j];
        const int cg = w * 4;
#pragma unroll
        for (int cc = 0; cc < 4; ++cc) {
            const int c = cg + cc;
            const unsigned short* qr = &Qs[lane * 280 + c * 16];
            short8 q0 = *(const short8*)qr;
            short8 q1 = *(const short8*)(qr + 8);
            float res = bf2f(Qs[lane * 280 + 256 + c]);
#pragma unroll
            for (int j = 0; j < 8; ++j) res += hv[j]     * bf2f((unsigned short)q0[j]);
#pragma unroll
            for (int j = 0; j < 8; ++j) res += hv[8 + j] * bf2f((unsigned short)q1[j]);
            out[(b * 16 + c) * 4096 + y * 64 + lane] = res;
        }
    }
}

extern "C" void kernel_launch(void* const* d_in, const int* in_sizes, int n_in,
                              void* d_out, int out_size, void* d_ws, size_t ws_size,
                              hipStream_t stream) {
    const float* x     = (const float*)d_in[0];
    const float* fc1_w = (const float*)d_in[1];
    const float* fc1_b = (const float*)d_in[2];
    const float* fc2_w = (const float*)d_in[3];
    const float* fc2_b = (const float*)d_in[4];
    float* out = (float*)d_out;
    unsigned short* Bfrag = (unsigned short*)d_ws;   // 85*64*8*2 = 87040 B

    prep_bfrag<<<85, 64, 0, stream>>>(fc2_w, fc2_b, Bfrag);
    sacconv_kernel<<<512, 256, 0, stream>>>(x, fc1_w, fc1_b, Bfrag, out);
}

// Round 8
// 72.160 us; speedup vs baseline: 1.1835x; 1.0449x over previous
//
#include <hip/hip_runtime.h>
#include <math.h>

// SACConv: B=8, C1=C2=16, K=3, S=1, H=W=64, HDIM=16, N=C1*K*K=144, L=4096
//
// out[b,l,c] = Qb[l,c] + sum_j h[l,j]*Qw[l,c*16+j]
//   Q[32768 x 272] = P[32768 x 144] @ Wcat[144 x 272]   (bf16 MFMA, K padded 160)
//   cols 0..255: (c,j) -> c*16+j from fc2_w ; cols 256..271: bias col c
//
// R8 = R7 + full B dedup + compile-time x addressing:
//  - lane (m,q) owns loc w*16+m, o-range [36q, 36q+36): c1/ii/jj all
//    compile-time (no runtime /9), loads issue as an early burst.
//  - A-frags staged to LDS with 4xb128+1xb64 per lane (phase depends on q&1).
//  - MFMA: wave w owns n-tiles {w, w+4, w+8, w+12} (+16 if w==3) for ALL 4
//    m-tiles -> each Bfrag byte read exactly once per block (44.6 MB total).
//  - B tile 0 loaded at kernel top, tile 1 before the barrier: stats phase
//    hides the L2 latency. 3 rotating B buffers, distance-2-ish prefetch.
//  - Barrier-free shuffle stats (validated R6/R7); 2 barriers total.

typedef __attribute__((ext_vector_type(8))) short short8;
typedef __attribute__((ext_vector_type(4))) float float4v;

#define NPq 144
#define QSTR 296   // Qs row stride (hw): 16B-aligned rows, free-conflict dump

__device__ __forceinline__ unsigned short f2bf(float f) {
    unsigned int u = __builtin_bit_cast(unsigned int, f);
    u += 0x7fffu + ((u >> 16) & 1u);
    return (unsigned short)(u >> 16);
}
__device__ __forceinline__ float bf2f(unsigned short h) {
    unsigned int u = ((unsigned int)h) << 16;
    return __builtin_bit_cast(float, u);
}

// ---------- prep: B fragments (unchanged, validated R3-R7) ----------
// Bfrag[(t*5+s)*64 + lane] = 8 bf16 of B[k = s*32+(lane>>4)*8+j][n = lane&15]
// t<16: B[k][n] = fc2_w[(t*144+k)*16+n]; t==16: fc2_b[n*144+k]; k>=144 -> 0
__global__ void prep_bfrag(const float* __restrict__ fc2_w,
                           const float* __restrict__ fc2_b,
                           unsigned short* __restrict__ Bfrag) {
    const int blk  = blockIdx.x;           // 85 = 17*5
    const int t    = blk / 5, s = blk % 5;
    const int lane = threadIdx.x;          // 64
    const int n    = lane & 15, q = lane >> 4;
    short8 v;
#pragma unroll
    for (int j = 0; j < 8; ++j) {
        const int k = s * 32 + q * 8 + j;
        float w = 0.f;
        if (k < NPq) w = (t < 16) ? fc2_w[(t * NPq + k) * 16 + n]
                                  : fc2_b[n * NPq + k];
        v[j] = (short)f2bf(w);
    }
    *(short8*)(Bfrag + (size_t)(blk * 64 + lane) * 8) = v;
}

// ---------- main ----------
__global__ __launch_bounds__(256, 2) void sacconv_kernel(
    const float* __restrict__ x,
    const float* __restrict__ fc1_w,
    const float* __restrict__ fc1_b,
    const unsigned short* __restrict__ Bfrag,
    float* __restrict__ out)
{
    __shared__ unsigned short SA[4 * 5 * 64 * 8];   // A-frags, 20480 B
    __shared__ unsigned short Qs[64 * QSTR];        // Q dump,  37888 B
    __shared__ float Hl[64][20];                    // h,        5120 B (63.5 KB)

    const int t   = threadIdx.x;
    const int blk = blockIdx.x;     // 512
    const int b   = blk >> 6;
    const int y   = blk & 63;

    const int lane = t & 63;
    const int w    = __builtin_amdgcn_readfirstlane(t >> 6);   // wave id
    const int m    = lane & 15;
    const int q    = lane >> 4;
    const int loc  = w * 16 + m;    // this lane's location

    // ---------- earliest possible B issue: tile w (hidden behind stats) ----------
    const short8* Bf = (const short8*)Bfrag;
    short8 bb0[5], bb1[5], bb2[5];
#pragma unroll
    for (int s = 0; s < 5; ++s) bb0[s] = Bf[(w * 5 + s) * 64 + lane];

    // ---------- x loads: o in [36q, 36q+36), compile-time c1/ii/jj ----------
    float v[36];
    float sum = 0.f, mx = -1e30f;
#pragma unroll
    for (int i = 0; i < 36; ++i) {
        const int g  = i / 9;               // compile-time
        const int r9 = i % 9;
        const int ii = r9 / 3, jj = r9 % 3; // compile-time
        const int yy = y + ii - 1;          // uniform condition
        const int xp = loc + jj - 1;        // per-lane
        float val = 0.f;
        if (yy >= 0 && yy < 64 && xp >= 0 && xp < 64)
            val = x[((b * 16 + 4 * q + g) * 64 + yy) * 64 + xp];
        v[i] = val;
        sum += val;
        mx  = fmaxf(mx, val);
    }

    // ---------- stage A-frags (lane's o-range -> 4xb128 + 1xb64, q-phase) ----------
    {
        unsigned int pk[18];
#pragma unroll
        for (int p = 0; p < 18; ++p)
            pk[p] = (unsigned int)f2bf(v[2 * p]) | ((unsigned int)f2bf(v[2 * p + 1]) << 16);
        const int g0 = (36 * q) >> 3;       // starting 8-group
        auto hwa = [&](int g) { return ((w * 5 + (g >> 2)) * 64 + (g & 3) * 16 + m) * 8; };
        if ((q & 1) == 0) {                 // phase 0: 4 full groups + trailing low half
#pragma unroll
            for (int u = 0; u < 4; ++u)
                *(uint4*)&SA[hwa(g0 + u)] = make_uint4(pk[4*u], pk[4*u+1], pk[4*u+2], pk[4*u+3]);
            *(uint2*)&SA[hwa(g0 + 4)] = make_uint2(pk[16], pk[17]);
        } else {                            // phase 4: leading high half + 4 full groups
            *(uint2*)&SA[hwa(g0) + 4] = make_uint2(pk[0], pk[1]);
#pragma unroll
            for (int u = 0; u < 4; ++u)
                *(uint4*)&SA[hwa(g0 + 1 + u)] = make_uint4(pk[4*u+2], pk[4*u+3], pk[4*u+4], pk[4*u+5]);
        }
        // zero K-pad k=144..159 (s=4, quads 2,3): 512 B per tile, lanes 0..31
        if (lane < 32)
            *(uint4*)&SA[((w * 5 + 4) * 64 + 32 + lane) * 8] = make_uint4(0u, 0u, 0u, 0u);
    }

    // ---------- shuffle stats (4 lanes m, m+16, m+32, m+48 share loc) ----------
    sum += __shfl_xor(sum, 16, 64);
    sum += __shfl_xor(sum, 32, 64);
    mx = fmaxf(mx, __shfl_xor(mx, 16, 64));
    mx = fmaxf(mx, __shfl_xor(mx, 32, 64));
    const float mu = sum * (1.f / 144.f);

    float m2 = 0.f, m3 = 0.f, m4 = 0.f, se = 0.f, sev = 0.f;
#pragma unroll
    for (int i = 0; i < 36; ++i) {
        const float d  = v[i] - mu;
        const float d2 = d * d;
        m2 += d2; m3 += d2 * d; m4 += d2 * d2;
        const float e = __expf(v[i] - mx);
        se += e; sev += e * v[i];
    }
    m2 += __shfl_xor(m2, 16, 64);  m2 += __shfl_xor(m2, 32, 64);
    m3 += __shfl_xor(m3, 16, 64);  m3 += __shfl_xor(m3, 32, 64);
    m4 += __shfl_xor(m4, 16, 64);  m4 += __shfl_xor(m4, 32, 64);
    se += __shfl_xor(se, 16, 64);  se += __shfl_xor(se, 32, 64);
    sev += __shfl_xor(sev, 16, 64); sev += __shfl_xor(sev, 32, 64);

    const float var   = m2 * (1.f / 143.f);           // ddof=1
    const float sigma = sqrtf(var) + 1e-6f;
    const float is    = 1.f / sigma;
    const float is2   = is * is;
    const float skew  = (m3 * (1.f / 144.f)) * is2 * is;
    const float kurt  = (m4 * (1.f / 144.f)) * is2 * is2 - 3.f;
    const float ent   = __logf(se) + mx - sev / se;   // validated R5-R7

    // ---------- h: lane (m,q) computes j = q*4..q*4+3 for its loc ----------
    {
        float h4[4];
#pragma unroll
        for (int j0 = 0; j0 < 4; ++j0) {
            const int j = q * 4 + j0;
            const float* wr = fc1_w + j * 5;
            const float hv = mu * wr[0] + sigma * wr[1] + skew * wr[2]
                           + kurt * wr[3] + ent * wr[4] + fc1_b[j];
            h4[j0] = fmaxf(hv, 0.f);
        }
        *(float4*)&Hl[loc][q * 4] = make_float4(h4[0], h4[1], h4[2], h4[3]);
    }

    // ---------- prefetch B tile w+4 before the barrier ----------
#pragma unroll
    for (int s = 0; s < 5; ++s) bb1[s] = Bf[((w + 4) * 5 + s) * 64 + lane];

    __syncthreads();   // barrier 1: A-frags + Hl visible

    // ---------- MFMA: wave w -> n-tiles {w, w+4, w+8, w+12} (+16 if w==3), all 4 m-tiles ----------
    short8 af[4][5];
#pragma unroll
    for (int mm = 0; mm < 4; ++mm)
#pragma unroll
        for (int s = 0; s < 5; ++s)
            af[mm][s] = *(const short8*)&SA[((mm * 5 + s) * 64 + lane) * 8];

    float4v acc[4][4];
#pragma unroll
    for (int u = 0; u < 4; ++u)
#pragma unroll
        for (int mm = 0; mm < 4; ++mm) acc[u][mm] = (float4v){0.f, 0.f, 0.f, 0.f};
    float4v acc4[4];
#pragma unroll
    for (int mm = 0; mm < 4; ++mm) acc4[mm] = (float4v){0.f, 0.f, 0.f, 0.f};

    // u=0: consume bb0 (tile w); prefetch tile w+8
#pragma unroll
    for (int s = 0; s < 5; ++s) bb2[s] = Bf[((w + 8) * 5 + s) * 64 + lane];
#pragma unroll
    for (int mm = 0; mm < 4; ++mm)
#pragma unroll
        for (int s = 0; s < 5; ++s)
            acc[0][mm] = __builtin_amdgcn_mfma_f32_16x16x32_bf16(af[mm][s], bb0[s], acc[0][mm], 0, 0, 0);

    // u=1: consume bb1 (tile w+4); prefetch tile w+12 into bb0
#pragma unroll
    for (int s = 0; s < 5; ++s) bb0[s] = Bf[((w + 12) * 5 + s) * 64 + lane];
#pragma unroll
    for (int mm = 0; mm < 4; ++mm)
#pragma unroll
        for (int s = 0; s < 5; ++s)
            acc[1][mm] = __builtin_amdgcn_mfma_f32_16x16x32_bf16(af[mm][s], bb1[s], acc[1][mm], 0, 0, 0);

    // u=2: consume bb2 (tile w+8); w==3 prefetches bias tile 16 into bb1
    if (w == 3) {
#pragma unroll
        for (int s = 0; s < 5; ++s) bb1[s] = Bf[(16 * 5 + s) * 64 + lane];
    }
#pragma unroll
    for (int mm = 0; mm < 4; ++mm)
#pragma unroll
        for (int s = 0; s < 5; ++s)
            acc[2][mm] = __builtin_amdgcn_mfma_f32_16x16x32_bf16(af[mm][s], bb2[s], acc[2][mm], 0, 0, 0);

    // u=3: consume bb0 (tile w+12)
#pragma unroll
    for (int mm = 0; mm < 4; ++mm)
#pragma unroll
        for (int s = 0; s < 5; ++s)
            acc[3][mm] = __builtin_amdgcn_mfma_f32_16x16x32_bf16(af[mm][s], bb0[s], acc[3][mm], 0, 0, 0);

    // u=4 (w==3 only): bias tile
    if (w == 3) {
#pragma unroll
        for (int mm = 0; mm < 4; ++mm)
#pragma unroll
            for (int s = 0; s < 5; ++s)
                acc4[mm] = __builtin_amdgcn_mfma_f32_16x16x32_bf16(af[mm][s], bb1[s], acc4[mm], 0, 0, 0);
    }

    // ---------- dump Q to its own LDS region (C layout: col=lane&15, row=(lane>>4)*4+r) ----------
    {
        const int nn = lane & 15, qq = lane >> 4;
#pragma unroll
        for (int u = 0; u < 4; ++u) {
            const int col = (w + 4 * u) * 16 + nn;
#pragma unroll
            for (int mm = 0; mm < 4; ++mm) {
                const int rowb = mm * 16 + qq * 4;
#pragma unroll
                for (int r = 0; r < 4; ++r)
                    Qs[(rowb + r) * QSTR + col] = f2bf(acc[u][mm][r]);
            }
        }
        if (w == 3) {
#pragma unroll
            for (int mm = 0; mm < 4; ++mm) {
                const int rowb = mm * 16 + qq * 4;
#pragma unroll
                for (int r = 0; r < 4; ++r)
                    Qs[(rowb + r) * QSTR + 256 + nn] = f2bf(acc4[mm][r]);
            }
        }
    }
    __syncthreads();   // barrier 2: Q complete

    // ---------- fold h, write out (lane = loc' 0..63, c-group w*4..w*4+3) ----------
    {
        float hv[16];
#pragma unroll
        for (int j = 0; j < 16; ++j) hv[j] = Hl[lane][j];
        const int cg = w * 4;
#pragma unroll
        for (int cc = 0; cc < 4; ++cc) {
            const int c = cg + cc;
            const unsigned short* qr = &Qs[lane * QSTR + c * 16];
            short8 q0 = *(const short8*)qr;
            short8 q1 = *(const short8*)(qr + 8);
            float res = bf2f(Qs[lane * QSTR + 256 + c]);
#pragma unroll
            for (int j = 0; j < 8; ++j) res += hv[j]     * bf2f((unsigned short)q0[j]);
#pragma unroll
            for (int j = 0; j < 8; ++j) res += hv[8 + j] * bf2f((unsigned short)q1[j]);
            out[(b * 16 + c) * 4096 + y * 64 + lane] = res;
        }
    }
}

extern "C" void kernel_launch(void* const* d_in, const int* in_sizes, int n_in,
                              void* d_out, int out_size, void* d_ws, size_t ws_size,
                              hipStream_t stream) {
    const float* x     = (const float*)d_in[0];
    const float* fc1_w = (const float*)d_in[1];
    const float* fc1_b = (const float*)d_in[2];
    const float* fc2_w = (const float*)d_in[3];
    const float* fc2_b = (const float*)d_in[4];
    float* out = (float*)d_out;
    unsigned short* Bfrag = (unsigned short*)d_ws;   // 85*64*8*2 = 87040 B

    prep_bfrag<<<85, 64, 0, stream>>>(fc2_w, fc2_b, Bfrag);
    sacconv_kernel<<<512, 256, 0, stream>>>(x, fc1_w, fc1_b, Bfrag, out);
}

// Round 9
// 70.689 us; speedup vs baseline: 1.2081x; 1.0208x over previous
//
#include <hip/hip_runtime.h>
#include <math.h>

// SACConv: B=8, C1=C2=16, K=3, S=1, H=W=64, HDIM=16, N=C1*K*K=144, L=4096
//
// out[b,l,c] = Qb[l,c] + sum_j h[l,j]*Qw[l,c*16+j]
//   Q[32768 x 272] = P[32768 x 144] @ Wcat[144 x 272]   (bf16 MFMA, K padded 160)
//   cols 0..255: (c,j) -> c*16+j from fc2_w ; cols 256..271: bias col c
//
// R9 = R8 + cooperative x staging through LDS (zero halo baked in):
//  - 3 coalesced float4 loads/thread stage rows {y-1,y,y+1} x 16ch into
//    Xs[ch][dy][68] (aliased into the Qs region; stride 68 -> 2-way banks = free).
//  - cols 64..67 + guard quad + invalid-y planes zeroed -> per-lane patch
//    gather is 36 UNconditional ds_read_b32 w/ immediate offsets (xp=-1 hits
//    the previous row's zeroed col 67, xp=64 hits col 64).
//  - everything downstream verbatim R8 (full B dedup, shuffle stats,
//    3-buffer B prefetch, Q dump, fold).

typedef __attribute__((ext_vector_type(8))) short short8;
typedef __attribute__((ext_vector_type(4))) float float4v;

#define NPq 144
#define QSTR 280   // Qs row stride (hw)

__device__ __forceinline__ unsigned short f2bf(float f) {
    unsigned int u = __builtin_bit_cast(unsigned int, f);
    u += 0x7fffu + ((u >> 16) & 1u);
    return (unsigned short)(u >> 16);
}
__device__ __forceinline__ float bf2f(unsigned short h) {
    unsigned int u = ((unsigned int)h) << 16;
    return __builtin_bit_cast(float, u);
}

// ---------- prep: B fragments (unchanged, validated R3-R8) ----------
// Bfrag[(t*5+s)*64 + lane] = 8 bf16 of B[k = s*32+(lane>>4)*8+j][n = lane&15]
// t<16: B[k][n] = fc2_w[(t*144+k)*16+n]; t==16: fc2_b[n*144+k]; k>=144 -> 0
__global__ void prep_bfrag(const float* __restrict__ fc2_w,
                           const float* __restrict__ fc2_b,
                           unsigned short* __restrict__ Bfrag) {
    const int blk  = blockIdx.x;           // 85 = 17*5
    const int t    = blk / 5, s = blk % 5;
    const int lane = threadIdx.x;          // 64
    const int n    = lane & 15, q = lane >> 4;
    short8 v;
#pragma unroll
    for (int j = 0; j < 8; ++j) {
        const int k = s * 32 + q * 8 + j;
        float w = 0.f;
        if (k < NPq) w = (t < 16) ? fc2_w[(t * NPq + k) * 16 + n]
                                  : fc2_b[n * NPq + k];
        v[j] = (short)f2bf(w);
    }
    *(short8*)(Bfrag + (size_t)(blk * 64 + lane) * 8) = v;
}

// ---------- main ----------
__global__ __launch_bounds__(256, 2) void sacconv_kernel(
    const float* __restrict__ x,
    const float* __restrict__ fc1_w,
    const float* __restrict__ fc1_b,
    const unsigned short* __restrict__ Bfrag,
    float* __restrict__ out)
{
    __shared__ unsigned short SA[4 * 5 * 64 * 8];                          // 20480 B
    __shared__ __attribute__((aligned(16))) unsigned short Qs[64 * QSTR];  // 35840 B
    __shared__ float Hl[64][20];                                           //  5120 B

    const int t   = threadIdx.x;
    const int blk = blockIdx.x;     // 512
    const int b   = blk >> 6;
    const int y   = blk & 63;

    const int lane = t & 63;
    const int w    = __builtin_amdgcn_readfirstlane(t >> 6);   // wave id
    const int m    = lane & 15;
    const int q    = lane >> 4;
    const int loc  = w * 16 + m;    // this lane's location

    // Xs aliases Qs (dead until Q dump, which is after barrier 2). Guard quad
    // at XsG[0..3] catches the ch=0,dy=0,xp=-1 underflow.
    float* XsG = (float*)Qs;
    float* Xs  = XsG + 4;           // Xs[ch*204 + dy*68 + col], col 0..67

    // ---------- earliest possible B issue: tile w (hidden behind staging/stats) ----------
    const short8* Bf = (const short8*)Bfrag;
    short8 bb0[5], bb1[5], bb2[5];
#pragma unroll
    for (int s = 0; s < 5; ++s) bb0[s] = Bf[(w * 5 + s) * 64 + lane];

    // ---------- stage x rows {y-1,y,y+1} x 16ch into Xs, halo zeroed ----------
    {
        const float4 z4 = make_float4(0.f, 0.f, 0.f, 0.f);
        // halo cols 64..67 of each of the 48 rows (row r = ch*3+dy -> addr r*68)
        if (t < 48) *(float4*)&Xs[t * 68 + 64] = z4;
        if (t == 48) *(float4*)&XsG[0] = z4;            // guard quad
        // invalid-y planes (block-uniform branch): dy plane fully zero
        const int ybad = (y == 0) ? 0 : ((y == 63) ? 2 : -1);
        if (ybad >= 0) {
#pragma unroll
            for (int u = 0; u < 2; ++u) {
                const int idx = t + 256 * u;            // < 272 = 16ch * 17quads
                if (idx < 272) {
                    const int ch = idx / 17, sg = idx % 17;
                    *(float4*)&Xs[ch * 204 + ybad * 68 + sg * 4] = z4;
                }
            }
        }
        // interior: 768 float4 = 48 rows x 16 segs, fully coalesced
#pragma unroll
        for (int u = 0; u < 3; ++u) {
            const int idx = t + 256 * u;                // < 768
            const int r  = idx >> 4, sg = idx & 15;
            const int ch = r / 3;
            const int dy = r - ch * 3;
            const int yy = y + dy - 1;
            if (yy >= 0 && yy < 64) {
                const float4 d = *(const float4*)&x[(((b * 16 + ch) * 64 + yy) << 6) + sg * 4];
                *(float4*)&Xs[r * 68 + sg * 4] = d;     // 16B-aligned
            }
        }
    }
    __syncthreads();   // barrier A: Xs complete

    // ---------- gather: 36 unconditional ds_read_b32 (2-way banks = free) ----------
    float v[36];
    float sum = 0.f, mx = -1e30f;
    {
        const float* basep = &Xs[q * 816 + loc - 1];    // + compile-time offsets
#pragma unroll
        for (int i = 0; i < 36; ++i) {
            const int g  = i / 9;               // compile-time
            const int r9 = i % 9;
            const int ii = r9 / 3, jj = r9 % 3; // compile-time
            const float val = basep[g * 204 + ii * 68 + jj];
            v[i] = val;
            sum += val;
            mx  = fmaxf(mx, val);
        }
    }

    // ---------- stage A-frags (lane's o-range [36q,36q+36) -> 4xb128+1xb64) ----------
    {
        unsigned int pk[18];
#pragma unroll
        for (int p = 0; p < 18; ++p)
            pk[p] = (unsigned int)f2bf(v[2 * p]) | ((unsigned int)f2bf(v[2 * p + 1]) << 16);
        const int g0 = (36 * q) >> 3;       // starting 8-group
        auto hwa = [&](int g) { return ((w * 5 + (g >> 2)) * 64 + (g & 3) * 16 + m) * 8; };
        if ((q & 1) == 0) {                 // phase 0: 4 full groups + trailing low half
#pragma unroll
            for (int u = 0; u < 4; ++u)
                *(uint4*)&SA[hwa(g0 + u)] = make_uint4(pk[4*u], pk[4*u+1], pk[4*u+2], pk[4*u+3]);
            *(uint2*)&SA[hwa(g0 + 4)] = make_uint2(pk[16], pk[17]);
        } else {                            // phase 4: leading high half + 4 full groups
            *(uint2*)&SA[hwa(g0) + 4] = make_uint2(pk[0], pk[1]);
#pragma unroll
            for (int u = 0; u < 4; ++u)
                *(uint4*)&SA[hwa(g0 + 1 + u)] = make_uint4(pk[4*u+2], pk[4*u+3], pk[4*u+4], pk[4*u+5]);
        }
        // zero K-pad k=144..159 (s=4, quads 2,3)
        if (lane < 32)
            *(uint4*)&SA[((w * 5 + 4) * 64 + 32 + lane) * 8] = make_uint4(0u, 0u, 0u, 0u);
    }

    // ---------- shuffle stats (4 lanes m, m+16, m+32, m+48 share loc) ----------
    sum += __shfl_xor(sum, 16, 64);
    sum += __shfl_xor(sum, 32, 64);
    mx = fmaxf(mx, __shfl_xor(mx, 16, 64));
    mx = fmaxf(mx, __shfl_xor(mx, 32, 64));
    const float mu = sum * (1.f / 144.f);

    float m2 = 0.f, m3 = 0.f, m4 = 0.f, se = 0.f, sev = 0.f;
#pragma unroll
    for (int i = 0; i < 36; ++i) {
        const float d  = v[i] - mu;
        const float d2 = d * d;
        m2 += d2; m3 += d2 * d; m4 += d2 * d2;
        const float e = __expf(v[i] - mx);
        se += e; sev += e * v[i];
    }
    m2 += __shfl_xor(m2, 16, 64);  m2 += __shfl_xor(m2, 32, 64);
    m3 += __shfl_xor(m3, 16, 64);  m3 += __shfl_xor(m3, 32, 64);
    m4 += __shfl_xor(m4, 16, 64);  m4 += __shfl_xor(m4, 32, 64);
    se += __shfl_xor(se, 16, 64);  se += __shfl_xor(se, 32, 64);
    sev += __shfl_xor(sev, 16, 64); sev += __shfl_xor(sev, 32, 64);

    const float var   = m2 * (1.f / 143.f);           // ddof=1
    const float sigma = sqrtf(var) + 1e-6f;
    const float is    = 1.f / sigma;
    const float is2   = is * is;
    const float skew  = (m3 * (1.f / 144.f)) * is2 * is;
    const float kurt  = (m4 * (1.f / 144.f)) * is2 * is2 - 3.f;
    const float ent   = __logf(se) + mx - sev / se;   // validated R5-R8

    // ---------- h: lane (m,q) computes j = q*4..q*4+3 for its loc ----------
    {
        float h4[4];
#pragma unroll
        for (int j0 = 0; j0 < 4; ++j0) {
            const int j = q * 4 + j0;
            const float* wr = fc1_w + j * 5;
            const float hv = mu * wr[0] + sigma * wr[1] + skew * wr[2]
                           + kurt * wr[3] + ent * wr[4] + fc1_b[j];
            h4[j0] = fmaxf(hv, 0.f);
        }
        *(float4*)&Hl[loc][q * 4] = make_float4(h4[0], h4[1], h4[2], h4[3]);
    }

    // ---------- prefetch B tile w+4 before the barrier ----------
#pragma unroll
    for (int s = 0; s < 5; ++s) bb1[s] = Bf[((w + 4) * 5 + s) * 64 + lane];

    __syncthreads();   // barrier 1: A-frags + Hl visible (Xs now dead)

    // ---------- MFMA: wave w -> n-tiles {w, w+4, w+8, w+12} (+16 if w==3), all 4 m-tiles ----------
    short8 af[4][5];
#pragma unroll
    for (int mm = 0; mm < 4; ++mm)
#pragma unroll
        for (int s = 0; s < 5; ++s)
            af[mm][s] = *(const short8*)&SA[((mm * 5 + s) * 64 + lane) * 8];

    float4v acc[4][4];
#pragma unroll
    for (int u = 0; u < 4; ++u)
#pragma unroll
        for (int mm = 0; mm < 4; ++mm) acc[u][mm] = (float4v){0.f, 0.f, 0.f, 0.f};
    float4v acc4[4];
#pragma unroll
    for (int mm = 0; mm < 4; ++mm) acc4[mm] = (float4v){0.f, 0.f, 0.f, 0.f};

    // u=0: consume bb0 (tile w); prefetch tile w+8
#pragma unroll
    for (int s = 0; s < 5; ++s) bb2[s] = Bf[((w + 8) * 5 + s) * 64 + lane];
#pragma unroll
    for (int mm = 0; mm < 4; ++mm)
#pragma unroll
        for (int s = 0; s < 5; ++s)
            acc[0][mm] = __builtin_amdgcn_mfma_f32_16x16x32_bf16(af[mm][s], bb0[s], acc[0][mm], 0, 0, 0);

    // u=1: consume bb1 (tile w+4); prefetch tile w+12 into bb0
#pragma unroll
    for (int s = 0; s < 5; ++s) bb0[s] = Bf[((w + 12) * 5 + s) * 64 + lane];
#pragma unroll
    for (int mm = 0; mm < 4; ++mm)
#pragma unroll
        for (int s = 0; s < 5; ++s)
            acc[1][mm] = __builtin_amdgcn_mfma_f32_16x16x32_bf16(af[mm][s], bb1[s], acc[1][mm], 0, 0, 0);

    // u=2: consume bb2 (tile w+8); w==3 prefetches bias tile 16 into bb1
    if (w == 3) {
#pragma unroll
        for (int s = 0; s < 5; ++s) bb1[s] = Bf[(16 * 5 + s) * 64 + lane];
    }
#pragma unroll
    for (int mm = 0; mm < 4; ++mm)
#pragma unroll
        for (int s = 0; s < 5; ++s)
            acc[2][mm] = __builtin_amdgcn_mfma_f32_16x16x32_bf16(af[mm][s], bb2[s], acc[2][mm], 0, 0, 0);

    // u=3: consume bb0 (tile w+12)
#pragma unroll
    for (int mm = 0; mm < 4; ++mm)
#pragma unroll
        for (int s = 0; s < 5; ++s)
            acc[3][mm] = __builtin_amdgcn_mfma_f32_16x16x32_bf16(af[mm][s], bb0[s], acc[3][mm], 0, 0, 0);

    // u=4 (w==3 only): bias tile
    if (w == 3) {
#pragma unroll
        for (int mm = 0; mm < 4; ++mm)
#pragma unroll
            for (int s = 0; s < 5; ++s)
                acc4[mm] = __builtin_amdgcn_mfma_f32_16x16x32_bf16(af[mm][s], bb1[s], acc4[mm], 0, 0, 0);
    }

    // ---------- dump Q to Qs (C layout: col=lane&15, row=(lane>>4)*4+r) ----------
    {
        const int nn = lane & 15, qq = lane >> 4;
#pragma unroll
        for (int u = 0; u < 4; ++u) {
            const int col = (w + 4 * u) * 16 + nn;
#pragma unroll
            for (int mm = 0; mm < 4; ++mm) {
                const int rowb = mm * 16 + qq * 4;
#pragma unroll
                for (int r = 0; r < 4; ++r)
                    Qs[(rowb + r) * QSTR + col] = f2bf(acc[u][mm][r]);
            }
        }
        if (w == 3) {
#pragma unroll
            for (int mm = 0; mm < 4; ++mm) {
                const int rowb = mm * 16 + qq * 4;
#pragma unroll
                for (int r = 0; r < 4; ++r)
                    Qs[(rowb + r) * QSTR + 256 + nn] = f2bf(acc4[mm][r]);
            }
        }
    }
    __syncthreads();   // barrier 2: Q complete

    // ---------- fold h, write out (lane = loc' 0..63, c-group w*4..w*4+3) ----------
    {
        float hv[16];
#pragma unroll
        for (int j = 0; j < 16; ++j) hv[j] = Hl[lane][j];
        const int cg = w * 4;
#pragma unroll
        for (int cc = 0; cc < 4; ++cc) {
            const int c = cg + cc;
            const unsigned short* qr = &Qs[lane * QSTR + c * 16];
            short8 q0 = *(const short8*)qr;
            short8 q1 = *(const short8*)(qr + 8);
            float res = bf2f(Qs[lane * QSTR + 256 + c]);
#pragma unroll
            for (int j = 0; j < 8; ++j) res += hv[j]     * bf2f((unsigned short)q0[j]);
#pragma unroll
            for (int j = 0; j < 8; ++j) res += hv[8 + j] * bf2f((unsigned short)q1[j]);
            out[(b * 16 + c) * 4096 + y * 64 + lane] = res;
        }
    }
}

extern "C" void kernel_launch(void* const* d_in, const int* in_sizes, int n_in,
                              void* d_out, int out_size, void* d_ws, size_t ws_size,
                              hipStream_t stream) {
    const float* x     = (const float*)d_in[0];
    const float* fc1_w = (const float*)d_in[1];
    const float* fc1_b = (const float*)d_in[2];
    const float* fc2_w = (const float*)d_in[3];
    const float* fc2_b = (const float*)d_in[4];
    float* out = (float*)d_out;
    unsigned short* Bfrag = (unsigned short*)d_ws;   // 85*64*8*2 = 87040 B

    prep_bfrag<<<85, 64, 0, stream>>>(fc2_w, fc2_b, Bfrag);
    sacconv_kernel<<<512, 256, 0, stream>>>(x, fc1_w, fc1_b, Bfrag, out);
}